// Round 3
// baseline (10433.829 us; speedup 1.0000x reference)
//
#include <hip/hip_runtime.h>
#include <stdint.h>

// Problem constants
#define B_      1024
#define T_      120
#define SENSORY 65
#define H_      512
#define RULE    64
#define NTASK   50
#define ENC_H   128
#define OUT_    33
#define IN_DIM  129     // RULE + SENSORY
#define G3      1536    // 3*H
#define INFO_DUR 20

// d_out layout (f32): out (B*T*33) | rnn_hid (B*T*512) | rule_enc (B*64)
#define OUT_ELEMS  (B_ * T_ * OUT_)
#define HID_ELEMS  (B_ * T_ * H_)
#define HID_OFF    OUT_ELEMS
#define RENC_OFF   (OUT_ELEMS + HID_ELEMS)

typedef __bf16 bf16;
typedef __bf16 bf16x8 __attribute__((ext_vector_type(8)));
typedef float  f32x4  __attribute__((ext_vector_type(4)));

#define MFMA_BF16(a, b, c) __builtin_amdgcn_mfma_f32_16x16x32_bf16((a), (b), (c), 0, 0, 0)

__device__ __forceinline__ float sigmoidf_(float x) {
    return 1.f / (1.f + __expf(-x));
}

// async global->LDS, 16B per lane; LDS dest = uniform base + lane*16
__device__ __forceinline__ void gload_lds16(const void* g, void* l) {
    __builtin_amdgcn_global_load_lds(
        (const __attribute__((address_space(1))) void*)g,
        (__attribute__((address_space(3))) void*)l, 16, 0, 0);
}

// Sense-reversal grid barrier (capture-safe; all blocks co-resident by
// construction: 80KB LDS -> <=2 blk/CU, grid 256 = #CUs, launch_bounds(512,2)).
// Bounded spin: a broken barrier degrades to wrong output, never a hang.
__device__ __forceinline__ void grid_barrier(unsigned* bar, unsigned* gen) {
    __syncthreads();
    if (threadIdx.x == 0) {
        __threadfence();   // release prior global stores (agent scope)
        unsigned g = __hip_atomic_load(gen, __ATOMIC_RELAXED, __HIP_MEMORY_SCOPE_AGENT);
        unsigned a = __hip_atomic_fetch_add(bar, 1u, __ATOMIC_ACQ_REL, __HIP_MEMORY_SCOPE_AGENT);
        if (a == gridDim.x - 1) {
            __hip_atomic_store(bar, 0u, __ATOMIC_RELAXED, __HIP_MEMORY_SCOPE_AGENT);
            __hip_atomic_store(gen, g + 1u, __ATOMIC_RELEASE, __HIP_MEMORY_SCOPE_AGENT);
        } else {
            int spins = 0;
            while (__hip_atomic_load(gen, __ATOMIC_ACQUIRE, __HIP_MEMORY_SCOPE_AGENT) == g) {
                __builtin_amdgcn_s_sleep(2);
                if (++spins > (1 << 20)) break;
            }
            __threadfence();  // acquire: invalidate L1 so whole block sees peers' data
        }
    }
    __syncthreads();
}

// ---------------------------------------------------------------------------
// Fragment-tile layout (all MFMA kernels):
// tile (16 rows x 32 k) = 64 slots of 8 bf16; slot s = kq*16 + row holds
// M[row][kq*8 .. +7].  MFMA lane l reads slot l (row=l&15, kq=l>>4). 1KB/tile.
// h frag global layout: tile index = kb*64 + mb (kb<16 over K=512, mb<64).
// ---------------------------------------------------------------------------

// h0 = 0.1 (bf16 hi/lo ping buffer 0) + barrier state init
__global__ void init_h_kernel(bf16* __restrict__ hhi, bf16* __restrict__ hlo,
                              unsigned* __restrict__ bar) {
    int i = blockIdx.x * 256 + threadIdx.x;   // grid exact: B*H/256
    bf16 hi = (bf16)0.1f;
    hhi[i] = hi;
    hlo[i] = (bf16)(0.1f - (float)hi);
    if (i == 0) { bar[0] = 0u; bar[1] = 0u; }
}

// w_hh (1536x512 f32) -> frag tiles, tile index = kb*96 + nb  (kb<16, nb<96)
__global__ void whh_prep_kernel(const float* __restrict__ w,
                                bf16* __restrict__ whi, bf16* __restrict__ wlo) {
    int gid = blockIdx.x * 256 + threadIdx.x;       // [0, 16*96*64)
    int tile = gid >> 6, slot = gid & 63;
    int kb = tile / 96, nb = tile % 96;
    int n = nb * 16 + (slot & 15);
    int k = kb * 32 + (slot >> 4) * 8;
    const float* src = w + (size_t)n * H_ + k;
    bf16x8 hv, lv;
#pragma unroll
    for (int e = 0; e < 8; ++e) {
        float v = src[e];
        bf16 h = (bf16)v;
        hv[e] = h;
        lv[e] = (bf16)(v - (float)h);
    }
    *(bf16x8*)(whi + (size_t)gid * 8) = hv;
    *(bf16x8*)(wlo + (size_t)gid * 8) = lv;
}

// w_ih[:, 64:129] (x-part), K padded 65->128, tile = kb*96 + nb (kb<4, nb<96)
// (scan uses kb 0,1 only; s=64 handled exactly in the epilogue)
__global__ void wih_prep_kernel(const float* __restrict__ wih,
                                bf16* __restrict__ whi, bf16* __restrict__ wlo) {
    int gid = blockIdx.x * 256 + threadIdx.x;       // [0, 4*96*64)
    int tile = gid >> 6, slot = gid & 63;
    int kb = tile / 96, nb = tile % 96;
    int n = nb * 16 + (slot & 15);
    int s0 = kb * 32 + (slot >> 4) * 8;
    bf16x8 hv, lv;
#pragma unroll
    for (int e = 0; e < 8; ++e) {
        int s = s0 + e;
        float v = (s < SENSORY) ? wih[(size_t)n * IN_DIM + RULE + s] : 0.f;
        bf16 h = (bf16)v;
        hv[e] = h;
        lv[e] = (bf16)(v - (float)h);
    }
    *(bf16x8*)(whi + (size_t)gid * 8) = hv;
    *(bf16x8*)(wlo + (size_t)gid * 8) = lv;
}

// out_w (33x512), N padded 33->48, tile = kb*3 + nb (kb<16, nb<3)
__global__ void outw_prep_kernel(const float* __restrict__ ow,
                                 bf16* __restrict__ whi, bf16* __restrict__ wlo) {
    int gid = blockIdx.x * 256 + threadIdx.x;       // [0, 16*3*64)
    int tile = gid >> 6, slot = gid & 63;
    int kb = tile / 3, nb = tile % 3;
    int n = nb * 16 + (slot & 15);
    int k = kb * 32 + (slot >> 4) * 8;
    bf16x8 hv, lv;
#pragma unroll
    for (int e = 0; e < 8; ++e) {
        float v = (n < OUT_) ? ow[(size_t)n * H_ + k + e] : 0.f;
        bf16 h = (bf16)v;
        hv[e] = h;
        lv[e] = (bf16)(v - (float)h);
    }
    *(bf16x8*)(whi + (size_t)gid * 8) = hv;
    *(bf16x8*)(wlo + (size_t)gid * 8) = lv;
}

// ---------------------------------------------------------------------------
// encoder (unchanged)
__global__ void __launch_bounds__(128) enc_kernel(
    const float* __restrict__ task_rule, const float* __restrict__ rule_transform,
    const float* __restrict__ enc_w1, const float* __restrict__ enc_b1,
    const float* __restrict__ enc_w2, const float* __restrict__ enc_b2,
    float* __restrict__ renc_out)
{
    int b = blockIdx.x;
    int tid = threadIdx.x;
    __shared__ float tr_s[NTASK];
    __shared__ float rt_s[RULE];
    __shared__ float h1_s[ENC_H];

    if (tid < NTASK) tr_s[tid] = task_rule[b * NTASK + tid];
    __syncthreads();
    if (tid < RULE) {
        float acc = 0.f;
        for (int n = 0; n < NTASK; ++n)
            acc += tr_s[n] * rule_transform[n * RULE + tid];
        rt_s[tid] = acc;
    }
    __syncthreads();
    {
        float acc = 0.f;
        for (int k = 0; k < RULE; ++k)
            acc += rt_s[k] * enc_w1[tid * RULE + k];
        acc += enc_b1[tid];
        h1_s[tid] = fmaxf(acc, 0.f);
    }
    __syncthreads();
    if (tid < RULE) {
        float acc = 0.f;
        for (int i = 0; i < ENC_H; ++i)
            acc += h1_s[i] * enc_w2[tid * ENC_H + i];
        acc += enc_b2[tid];
        renc_out[b * RULE + tid] = fmaxf(acc, 0.f);
    }
}

// rule_gi[b][g] = renc[b][:64] . w_ih[g][:64]  (f32, unchanged)
__global__ void __launch_bounds__(256) rulegi_kernel(
    const float* __restrict__ renc, const float* __restrict__ w_ih,
    float* __restrict__ rule_gi)
{
    int id = blockIdx.x * 256 + threadIdx.x;
    int b = id / G3, g = id % G3;
    const float* r = renc + b * RULE;
    const float* w = w_ih + (size_t)g * IN_DIM;
    float acc = 0.f;
#pragma unroll 8
    for (int k = 0; k < RULE; ++k) acc += r[k] * w[k];
    rule_gi[id] = acc;
}

// ---------------------------------------------------------------------------
// Persistent GRU scan: all 120 steps in one kernel, manual grid barrier
// between steps.  Block tile 64 batch x 32 j (x3 gates); 8 waves (mw<4, jw<2),
// wave tile 16b x 16j x 3 gates.  K-loop per step: 8 h-chunks (K=64 each) +
// 1 x-chunk (s 0..63); s=64 is an exact f32 rank-1 update in the epilogue.
// Grid 256 = 16bx x 16by, by = id&15 so each XCD owns 2 j-slices of w_hh
// (L2-resident all scan).  h carried in registers (hprev); bf16 hi/lo
// fragment ping-pong through global for the cross-block A-tiles.
// LDS: 2 bufs x (A 16KB + B 24KB) = 80KB.
__global__ void __launch_bounds__(512, 2) scan_kernel(
    float* __restrict__ hid,
    bf16* __restrict__ ph_hi0, bf16* __restrict__ ph_lo0,
    bf16* __restrict__ ph_hi1, bf16* __restrict__ ph_lo1,
    const bf16* __restrict__ whh_hi, const bf16* __restrict__ whh_lo,
    const bf16* __restrict__ wih_hi, const bf16* __restrict__ wih_lo,
    const float* __restrict__ x, const float* __restrict__ rule_gi,
    const float* __restrict__ b_ih, const float* __restrict__ b_hh,
    const float* __restrict__ w_ih, unsigned* __restrict__ barrier_ws)
{
    __shared__ __align__(16) unsigned char smem[81920];

    const int tid  = threadIdx.x;
    const int w    = tid >> 6;
    const int lane = tid & 63;
    const int id   = blockIdx.x;
    const int by   = id & 15;          // j-slice: XCD-pinned (id%8 -> {x,x+8})
    const int bx   = id >> 4;          // batch-slice
    const int b0   = bx * 64;
    const int mw   = w & 3;
    const int jw   = w >> 2;

    const int jj  = by * 32 + jw * 16 + (lane & 15);
    const int bb0 = b0 + mw * 16 + ((lane >> 4) << 2);

    // hoisted t-invariant scalars
    const float bihr = b_ih[jj], bihz = b_ih[H_ + jj], bihn = b_ih[2 * H_ + jj];
    const float bhhr = b_hh[jj], bhhz = b_hh[H_ + jj], bhhn = b_hh[2 * H_ + jj];
    const float w64r = w_ih[(size_t)jj * IN_DIM + 128];
    const float w64z = w_ih[(size_t)(H_ + jj) * IN_DIM + 128];
    const float w64n = w_ih[(size_t)(2 * H_ + jj) * IN_DIM + 128];
    float rg0[4], rg1[4], rg2[4];
#pragma unroll
    for (int r = 0; r < 4; ++r) {
        const float* rp = rule_gi + (size_t)(bb0 + r) * G3 + jj;
        rg0[r] = rp[0]; rg1[r] = rp[H_]; rg2[r] = rp[2 * H_];
    }
    float hprev[4] = {0.1f, 0.1f, 0.1f, 0.1f};
    const size_t tb   = (size_t)(by * 64 + bx * 4 + mw) * 512;
    const int    scol = ((jj >> 3) & 3) * 16;

    f32x4 acc0, acc1, acc2, acc3;
    const f32x4 zero4 = {0.f, 0.f, 0.f, 0.f};

#pragma unroll 1
    for (int t = 0; t < T_; ++t) {
        const bf16* hinhi = (t & 1) ? ph_hi1 : ph_hi0;
        const bf16* hinlo = (t & 1) ? ph_lo1 : ph_lo0;
        bf16* houthi = (t & 1) ? ph_hi0 : ph_hi1;
        bf16* houtlo = (t & 1) ? ph_lo0 : ph_lo1;
        acc0 = zero4; acc1 = zero4; acc2 = zero4; acc3 = zero4;

        // stage chunk c into buf: 40 x 1KB tiles, 5 per wave.
        // c<8: A = h frags (16 tiles), B = w_hh (24).  c==8: B = w_ih kb 0,1.
        auto stage = [&](int c, int buf) {
            uint8_t* base = smem + buf * 40960;
#pragma unroll
            for (int i = 0; i < 5; ++i) {
                const int u = w * 5 + i;
                if (u < 16) {
                    if (c < 8) {
                        const int mbl = u & 3, kbl = (u >> 2) & 1, hh = u >> 3;
                        const bf16* src = (hh ? hinlo : hinhi)
                            + ((size_t)((2 * c + kbl) * 64 + bx * 4 + mbl)) * 512
                            + lane * 8;
                        gload_lds16(src, base + u * 1024);
                    }
                } else {
                    const int u2 = u - 16;
                    const int nbl = u2 % 6, kbl = (u2 / 6) & 1, hh = u2 / 12;
                    const int nb = (nbl >> 1) * 32 + by * 2 + (nbl & 1);
                    const bf16* src = (c < 8)
                        ? (hh ? whh_lo : whh_hi) + ((size_t)((2 * c + kbl) * 96 + nb)) * 512
                        : (hh ? wih_lo : wih_hi) + ((size_t)(kbl * 96 + nb)) * 512;
                    gload_lds16(src + lane * 8, base + 16384 + u2 * 1024);
                }
            }
        };
        auto compute = [&](int buf, bool isx) {
            uint8_t* base = smem + buf * 40960;
#pragma unroll
            for (int kbl = 0; kbl < 2; ++kbl) {
                const bf16* ab = (const bf16*)(base + (mw + 4 * kbl) * 1024) + lane * 8;
                const bf16x8 ahi = *(const bf16x8*)ab;
                const bf16x8 alo = *(const bf16x8*)(ab + 8 * 512);
                const bf16* bp = (const bf16*)(base + 16384) + lane * 8;
#pragma unroll
                for (int g = 0; g < 3; ++g) {
                    const bf16x8 bhi = *(const bf16x8*)(bp + ((g * 2 + jw) + 6 * kbl) * 512);
                    const bf16x8 blo = *(const bf16x8*)(bp + ((g * 2 + jw) + 6 * kbl + 12) * 512);
                    f32x4* ap = (g == 0) ? &acc0 : (g == 1) ? &acc1
                              : (isx ? &acc3 : &acc2);
                    *ap = MFMA_BF16(ahi, bhi, *ap);
                    *ap = MFMA_BF16(alo, bhi, *ap);
                    *ap = MFMA_BF16(ahi, blo, *ap);
                }
            }
        };

        stage(0, 0);
        __syncthreads();
#pragma unroll
        for (int c = 0; c < 8; ++c) {
            stage(c + 1, (c + 1) & 1);
            if (c == 7) {
                // build x A-tiles (s 0..63, hi/lo) into buf 0 for chunk 8
                uint8_t* base = smem;            // buf 0
                const int bl = tid >> 3, s0 = (tid & 7) * 8;
                const float* xs = x + ((size_t)(b0 + bl) * T_ + t) * SENSORY + s0;
                float v[8];
#pragma unroll
                for (int e = 0; e < 8; ++e) v[e] = xs[e];
                bf16x8 hv, lv;
#pragma unroll
                for (int e = 0; e < 8; ++e) {
                    bf16 h = (bf16)v[e];
                    hv[e] = h;
                    lv[e] = (bf16)(v[e] - (float)h);
                }
                const int tile = (bl >> 4) + 4 * (s0 >> 5);
                const int sl = (((s0 >> 3) & 3) * 16 + (bl & 15)) * 16;
                *(bf16x8*)(base + tile * 1024 + sl) = hv;
                *(bf16x8*)(base + (tile + 8) * 1024 + sl) = lv;
            }
            compute(c & 1, false);
            __syncthreads();
        }
        compute(0, true);

        // ---- epilogue: gates + state update + exact s=64 rank-1 ----
        const bool use_rule = (t < INFO_DUR);
#pragma unroll
        for (int r = 0; r < 4; ++r) {
            const int b = bb0 + r;
            const float xv = x[((size_t)b * T_ + t) * SENSORY + 64];
            const float ar = use_rule ? rg0[r] : 0.f;
            const float az = use_rule ? rg1[r] : 0.f;
            const float an = use_rule ? rg2[r] : 0.f;
            const float rr = sigmoidf_(acc0[r] + bihr + bhhr + ar + xv * w64r);
            const float zz = sigmoidf_(acc1[r] + bihz + bhhz + az + xv * w64z);
            const float hn = acc2[r] + bhhn;
            const float in = acc3[r] + bihn + an + xv * w64n;
            const float nn = fmaxf(in + rr * hn, 0.f);
            const float hnew = (1.f - zz) * nn + zz * hprev[r];
            hprev[r] = hnew;
            hid[(size_t)b * (T_ * H_) + (size_t)t * H_ + jj] = hnew;
            const bf16 hi = (bf16)hnew;
            const bf16 lo = (bf16)(hnew - (float)hi);
            const size_t ha = tb + (size_t)(scol + (b & 15)) * 8 + (jj & 7);
            houthi[ha] = hi;
            houtlo[ha] = lo;
        }
        grid_barrier(barrier_ws, barrier_ws + 1);
    }
}

// ---------------------------------------------------------------------------
// out = sigmoid(hid @ out_w^T + b): MFMA, N padded 33->48, 64 rows/block.
__global__ void __launch_bounds__(256) out_kernel(
    const float* __restrict__ hid,
    const bf16* __restrict__ owhi, const bf16* __restrict__ owlo,
    const float* __restrict__ out_b, float* __restrict__ out)
{
    __shared__ __align__(16) unsigned char smem[28672];
    bf16* const A  = (bf16*)smem;            // 16 tiles: mbl + 4*kbl + 8*hh
    bf16* const Bf = (bf16*)(smem + 16384);  // 12 tiles: nbl + 3*kbl + 6*hh
    const int tid = threadIdx.x, w = tid >> 6, lane = tid & 63;
    const int bt0 = blockIdx.x * 64;

    f32x4 acc0 = {0.f, 0.f, 0.f, 0.f};
    f32x4 acc1 = {0.f, 0.f, 0.f, 0.f};
    f32x4 acc2 = {0.f, 0.f, 0.f, 0.f};

#pragma unroll 1
    for (int c = 0; c < 8; ++c) {            // K chunks of 64
        __syncthreads();
#pragma unroll
        for (int i = 0; i < 3; ++i) {
            const int u = w * 3 + i;
            const int nbl = u % 3, kbl = (u / 3) & 1, hh = u / 6;
            const bf16* src = (hh ? owlo : owhi)
                + ((size_t)((2 * c + kbl) * 3 + nbl)) * 512 + lane * 8;
            gload_lds16(src, Bf + u * 512);
        }
#pragma unroll
        for (int it = 0; it < 2; ++it) {
            const int v = tid + it * 256;
            const int row = v >> 3, kq = v & 7;
            const float* src = hid + (size_t)(bt0 + row) * H_ + c * 64 + kq * 8;
            const f32x4 v0 = *(const f32x4*)src;
            const f32x4 v1 = *(const f32x4*)(src + 4);
            bf16x8 hv, lv;
#pragma unroll
            for (int e = 0; e < 4; ++e) {
                bf16 h0 = (bf16)v0[e]; hv[e] = h0;     lv[e] = (bf16)(v0[e] - (float)h0);
                bf16 h1 = (bf16)v1[e]; hv[4 + e] = h1; lv[4 + e] = (bf16)(v1[e] - (float)h1);
            }
            const int at = (row >> 4) + 4 * (kq >> 2);
            const int sl = ((kq & 3) * 16 + (row & 15)) * 8;
            *(bf16x8*)(A + at * 512 + sl) = hv;
            *(bf16x8*)(A + (at + 8) * 512 + sl) = lv;
        }
        __syncthreads();
#pragma unroll
        for (int kbl = 0; kbl < 2; ++kbl) {
            const bf16* ab = A + (w + 4 * kbl) * 512 + lane * 8;
            const bf16x8 ahi = *(const bf16x8*)ab;
            const bf16x8 alo = *(const bf16x8*)(ab + 8 * 512);
            const bf16* bb = Bf + (3 * kbl) * 512 + lane * 8;
            {   const bf16x8 bhi = *(const bf16x8*)bb;
                const bf16x8 blo = *(const bf16x8*)(bb + 6 * 512);
                acc0 = MFMA_BF16(ahi, bhi, acc0);
                acc0 = MFMA_BF16(alo, bhi, acc0);
                acc0 = MFMA_BF16(ahi, blo, acc0); }
            {   const bf16x8 bhi = *(const bf16x8*)(bb + 512);
                const bf16x8 blo = *(const bf16x8*)(bb + 7 * 512);
                acc1 = MFMA_BF16(ahi, bhi, acc1);
                acc1 = MFMA_BF16(alo, bhi, acc1);
                acc1 = MFMA_BF16(ahi, blo, acc1); }
            {   const bf16x8 bhi = *(const bf16x8*)(bb + 2 * 512);
                const bf16x8 blo = *(const bf16x8*)(bb + 8 * 512);
                acc2 = MFMA_BF16(ahi, bhi, acc2);
                acc2 = MFMA_BF16(alo, bhi, acc2);
                acc2 = MFMA_BF16(ahi, blo, acc2); }
        }
    }
    const int col = lane & 15, rb = (lane >> 4) * 4;
#pragma unroll
    for (int nb = 0; nb < 3; ++nb) {
        const int o = nb * 16 + col;
        if (o < OUT_) {
            const float ob = out_b[o];
            const f32x4 a = (nb == 0) ? acc0 : (nb == 1) ? acc1 : acc2;
#pragma unroll
            for (int r = 0; r < 4; ++r) {
                const int row = bt0 + w * 16 + rb + r;
                out[(size_t)row * OUT_ + o] = sigmoidf_(a[r] + ob);
            }
        }
    }
}

// ---------------------------------------------------------------------------
extern "C" void kernel_launch(void* const* d_in, const int* in_sizes, int n_in,
                              void* d_out, int out_size, void* d_ws, size_t ws_size,
                              hipStream_t stream)
{
    const float* x              = (const float*)d_in[0];
    const float* task_rule      = (const float*)d_in[1];
    const float* rule_transform = (const float*)d_in[2];
    const float* enc_w1         = (const float*)d_in[3];
    const float* enc_b1         = (const float*)d_in[4];
    const float* enc_w2         = (const float*)d_in[5];
    const float* enc_b2         = (const float*)d_in[6];
    const float* w_ih           = (const float*)d_in[7];
    const float* w_hh           = (const float*)d_in[8];
    const float* b_ih           = (const float*)d_in[9];
    const float* b_hh           = (const float*)d_in[10];
    const float* out_w          = (const float*)d_in[11];
    const float* out_b          = (const float*)d_in[12];

    float* out_p  = (float*)d_out;
    float* hid_p  = (float*)d_out + HID_OFF;
    float* renc_p = (float*)d_out + RENC_OFF;

    // workspace layout (bytes), total 14,516,256
    uint8_t* wsb = (uint8_t*)d_ws;
    float* rule_gi = (float*)(wsb + 0);            // B*G3*4   = 6,291,456
    bf16* hh0   = (bf16*)(wsb +  6291456);         // B*H*2    = 1,048,576 each
    bf16* hl0   = (bf16*)(wsb +  7340032);
    bf16* hh1   = (bf16*)(wsb +  8388608);
    bf16* hl1   = (bf16*)(wsb +  9437184);
    bf16* whhhi = (bf16*)(wsb + 10485760);         // G3*H*2   = 1,572,864
    bf16* whhlo = (bf16*)(wsb + 12058624);
    bf16* wihhi = (bf16*)(wsb + 13631488);         // G3*128*2 =   393,216
    bf16* wihlo = (bf16*)(wsb + 14024704);
    bf16* owhi  = (bf16*)(wsb + 14417920);         // 48*512*2 =    49,152
    bf16* owlo  = (bf16*)(wsb + 14467072);
    unsigned* barp = (unsigned*)(wsb + 14516224);  // 2 x u32 barrier state

    init_h_kernel<<<(B_ * H_) / 256, 256, 0, stream>>>(hh0, hl0, barp);
    whh_prep_kernel<<<384, 256, 0, stream>>>(w_hh, whhhi, whhlo);
    wih_prep_kernel<<<96, 256, 0, stream>>>(w_ih, wihhi, wihlo);
    outw_prep_kernel<<<12, 256, 0, stream>>>(out_w, owhi, owlo);
    enc_kernel<<<B_, 128, 0, stream>>>(task_rule, rule_transform, enc_w1, enc_b1,
                                       enc_w2, enc_b2, renc_p);
    rulegi_kernel<<<(B_ * G3) / 256, 256, 0, stream>>>(renc_p, w_ih, rule_gi);

    // persistent scan: 256 blocks (16bx x 16by) x 512 threads, manual barrier
    scan_kernel<<<dim3(256), dim3(512), 0, stream>>>(
        hid_p, hh0, hl0, hh1, hl1, whhhi, whhlo, wihhi, wihlo,
        x, rule_gi, b_ih, b_hh, w_ih, barp);

    out_kernel<<<(B_ * T_) / 64, 256, 0, stream>>>(hid_p, owhi, owlo, out_b, out_p);
}

// Round 5
// 4732.669 us; speedup vs baseline: 2.2046x; 2.2046x over previous
//
#include <hip/hip_runtime.h>
#include <stdint.h>

// Problem constants
#define B_      1024
#define T_      120
#define SENSORY 65
#define H_      512
#define RULE    64
#define NTASK   50
#define ENC_H   128
#define OUT_    33
#define IN_DIM  129     // RULE + SENSORY
#define G3      1536    // 3*H
#define INFO_DUR 20

// d_out layout (f32): out (B*T*33) | rnn_hid (B*T*512) | rule_enc (B*64)
#define OUT_ELEMS  (B_ * T_ * OUT_)
#define HID_ELEMS  (B_ * T_ * H_)
#define HID_OFF    OUT_ELEMS
#define RENC_OFF   (OUT_ELEMS + HID_ELEMS)

typedef __bf16 bf16;
typedef __bf16 bf16x8 __attribute__((ext_vector_type(8)));
typedef float  f32x4  __attribute__((ext_vector_type(4)));

#define MFMA_BF16(a, b, c) __builtin_amdgcn_mfma_f32_16x16x32_bf16((a), (b), (c), 0, 0, 0)

__device__ __forceinline__ float sigmoidf_(float x) {
    return 1.f / (1.f + __expf(-x));
}

// async global->LDS, 16B per lane; LDS dest = uniform base + lane*16
__device__ __forceinline__ void gload_lds16(const void* g, void* l) {
    __builtin_amdgcn_global_load_lds(
        (const __attribute__((address_space(1))) void*)g,
        (__attribute__((address_space(3))) void*)l, 16, 0, 0);
}

// ---------------------------------------------------------------------------
// Fragment-tile layout (all MFMA kernels):
// tile (16 rows x 32 k) = 64 slots of 8 bf16; slot s = kq*16 + row holds
// M[row][kq*8 .. +7].  MFMA lane l reads slot l (row=l&15, kq=l>>4). 1KB/tile.
// h frag global layout: tile index = kb*64 + mb (kb<16 over K=512, mb<64).
// ---------------------------------------------------------------------------

// h0 = 0.1 (f32 + bf16 hi/lo ping buffer 0)
__global__ void init_h_kernel(float* __restrict__ h, bf16* __restrict__ hhi,
                              bf16* __restrict__ hlo) {
    int i = blockIdx.x * 256 + threadIdx.x;   // grid exact: B*H/256
    h[i] = 0.1f;
    bf16 hi = (bf16)0.1f;
    hhi[i] = hi;
    hlo[i] = (bf16)(0.1f - (float)hi);
}

// w_hh (1536x512 f32) -> frag tiles, tile index = kb*96 + nb  (kb<16, nb<96)
__global__ void whh_prep_kernel(const float* __restrict__ w,
                                bf16* __restrict__ whi, bf16* __restrict__ wlo) {
    int gid = blockIdx.x * 256 + threadIdx.x;       // [0, 16*96*64)
    int tile = gid >> 6, slot = gid & 63;
    int kb = tile / 96, nb = tile % 96;
    int n = nb * 16 + (slot & 15);
    int k = kb * 32 + (slot >> 4) * 8;
    const float* src = w + (size_t)n * H_ + k;
    bf16x8 hv, lv;
#pragma unroll
    for (int e = 0; e < 8; ++e) {
        float v = src[e];
        bf16 h = (bf16)v;
        hv[e] = h;
        lv[e] = (bf16)(v - (float)h);
    }
    *(bf16x8*)(whi + (size_t)gid * 8) = hv;
    *(bf16x8*)(wlo + (size_t)gid * 8) = lv;
}

// w_ih[:, 64:129] (x-part), K padded 65->128, tile = kb*96 + nb (kb<4, nb<96)
// (step uses kb 0,1 only; s=64 handled exactly in the epilogue)
__global__ void wih_prep_kernel(const float* __restrict__ wih,
                                bf16* __restrict__ whi, bf16* __restrict__ wlo) {
    int gid = blockIdx.x * 256 + threadIdx.x;       // [0, 4*96*64)
    int tile = gid >> 6, slot = gid & 63;
    int kb = tile / 96, nb = tile % 96;
    int n = nb * 16 + (slot & 15);
    int s0 = kb * 32 + (slot >> 4) * 8;
    bf16x8 hv, lv;
#pragma unroll
    for (int e = 0; e < 8; ++e) {
        int s = s0 + e;
        float v = (s < SENSORY) ? wih[(size_t)n * IN_DIM + RULE + s] : 0.f;
        bf16 h = (bf16)v;
        hv[e] = h;
        lv[e] = (bf16)(v - (float)h);
    }
    *(bf16x8*)(whi + (size_t)gid * 8) = hv;
    *(bf16x8*)(wlo + (size_t)gid * 8) = lv;
}

// out_w (33x512), N padded 33->48, tile = kb*3 + nb (kb<16, nb<3)
__global__ void outw_prep_kernel(const float* __restrict__ ow,
                                 bf16* __restrict__ whi, bf16* __restrict__ wlo) {
    int gid = blockIdx.x * 256 + threadIdx.x;       // [0, 16*3*64)
    int tile = gid >> 6, slot = gid & 63;
    int kb = tile / 3, nb = tile % 3;
    int n = nb * 16 + (slot & 15);
    int k = kb * 32 + (slot >> 4) * 8;
    bf16x8 hv, lv;
#pragma unroll
    for (int e = 0; e < 8; ++e) {
        float v = (n < OUT_) ? ow[(size_t)n * H_ + k + e] : 0.f;
        bf16 h = (bf16)v;
        hv[e] = h;
        lv[e] = (bf16)(v - (float)h);
    }
    *(bf16x8*)(whi + (size_t)gid * 8) = hv;
    *(bf16x8*)(wlo + (size_t)gid * 8) = lv;
}

// ---------------------------------------------------------------------------
// encoder (unchanged)
__global__ void __launch_bounds__(128) enc_kernel(
    const float* __restrict__ task_rule, const float* __restrict__ rule_transform,
    const float* __restrict__ enc_w1, const float* __restrict__ enc_b1,
    const float* __restrict__ enc_w2, const float* __restrict__ enc_b2,
    float* __restrict__ renc_out)
{
    int b = blockIdx.x;
    int tid = threadIdx.x;
    __shared__ float tr_s[NTASK];
    __shared__ float rt_s[RULE];
    __shared__ float h1_s[ENC_H];

    if (tid < NTASK) tr_s[tid] = task_rule[b * NTASK + tid];
    __syncthreads();
    if (tid < RULE) {
        float acc = 0.f;
        for (int n = 0; n < NTASK; ++n)
            acc += tr_s[n] * rule_transform[n * RULE + tid];
        rt_s[tid] = acc;
    }
    __syncthreads();
    {
        float acc = 0.f;
        for (int k = 0; k < RULE; ++k)
            acc += rt_s[k] * enc_w1[tid * RULE + k];
        acc += enc_b1[tid];
        h1_s[tid] = fmaxf(acc, 0.f);
    }
    __syncthreads();
    if (tid < RULE) {
        float acc = 0.f;
        for (int i = 0; i < ENC_H; ++i)
            acc += h1_s[i] * enc_w2[tid * ENC_H + i];
        acc += enc_b2[tid];
        renc_out[b * RULE + tid] = fmaxf(acc, 0.f);
    }
}

// rule_gi[b][g] = renc[b][:64] . w_ih[g][:64]  (f32, unchanged)
__global__ void __launch_bounds__(256) rulegi_kernel(
    const float* __restrict__ renc, const float* __restrict__ w_ih,
    float* __restrict__ rule_gi)
{
    int id = blockIdx.x * 256 + threadIdx.x;
    int b = id / G3, g = id % G3;
    const float* r = renc + b * RULE;
    const float* w = w_ih + (size_t)g * IN_DIM;
    float acc = 0.f;
#pragma unroll 8
    for (int k = 0; k < RULE; ++k) acc += r[k] * w[k];
    rule_gi[id] = acc;
}

// ---------------------------------------------------------------------------
// One GRU step (launch per t; launch boundary provides cross-step coherence).
// Block tile 64 batch x 32 j (x3 gates); 8 waves (mw<4, jw<2), wave tile
// 16b x 16j x 3 gates.  K-loop: 8 h-chunks (K=64 each) + 1 x-chunk (s 0..63);
// s=64 is an exact f32 rank-1 update in the epilogue.
// Grid 256 (1D): by = id&15 (XCD-pinned j-slice for weight L2 locality,
// perf-only), bx = id>>4.  LDS: 2 bufs x (A 16KB + B 24KB) = 80KB.
__global__ void __launch_bounds__(512, 2) step_kernel(
    float* __restrict__ hid,
    const float* __restrict__ h_src, int hs_stride,
    const bf16* __restrict__ hin_hi, const bf16* __restrict__ hin_lo,
    bf16* __restrict__ hout_hi, bf16* __restrict__ hout_lo,
    const bf16* __restrict__ whh_hi, const bf16* __restrict__ whh_lo,
    const bf16* __restrict__ wih_hi, const bf16* __restrict__ wih_lo,
    const float* __restrict__ x, const float* __restrict__ rule_gi,
    const float* __restrict__ b_ih, const float* __restrict__ b_hh,
    const float* __restrict__ w_ih, int t)
{
    __shared__ __align__(16) unsigned char smem[81920];

    const int tid  = threadIdx.x;
    const int w    = tid >> 6;
    const int lane = tid & 63;
    const int id   = blockIdx.x;
    const int by   = id & 15;
    const int bx   = id >> 4;
    const int b0   = bx * 64;
    const int mw   = w & 3;
    const int jw   = w >> 2;

    const int jj  = by * 32 + jw * 16 + (lane & 15);
    const int bb0 = b0 + mw * 16 + ((lane >> 4) << 2);

    f32x4 acc0 = {0.f, 0.f, 0.f, 0.f};   // r   (h-part + x-part)
    f32x4 acc1 = {0.f, 0.f, 0.f, 0.f};   // z   (h-part + x-part)
    f32x4 acc2 = {0.f, 0.f, 0.f, 0.f};   // h_n (h-part only)
    f32x4 acc3 = {0.f, 0.f, 0.f, 0.f};   // i_n (x-part only)

    // stage chunk c into buf: 40 x 1KB tiles, 5 per wave.
    // c<8: A = h frags (16 tiles), B = w_hh (24).  c==8: B = w_ih kb 0,1.
    auto stage = [&](int c, int buf) {
        uint8_t* base = smem + buf * 40960;
#pragma unroll
        for (int i = 0; i < 5; ++i) {
            const int u = w * 5 + i;
            if (u < 16) {
                if (c < 8) {
                    const int mbl = u & 3, kbl = (u >> 2) & 1, hh = u >> 3;
                    const bf16* src = (hh ? hin_lo : hin_hi)
                        + ((size_t)((2 * c + kbl) * 64 + bx * 4 + mbl)) * 512
                        + lane * 8;
                    gload_lds16(src, base + u * 1024);
                }
            } else {
                const int u2 = u - 16;
                const int nbl = u2 % 6, kbl = (u2 / 6) & 1, hh = u2 / 12;
                const int nb = (nbl >> 1) * 32 + by * 2 + (nbl & 1);
                const bf16* src = (c < 8)
                    ? (hh ? whh_lo : whh_hi) + ((size_t)((2 * c + kbl) * 96 + nb)) * 512
                    : (hh ? wih_lo : wih_hi) + ((size_t)(kbl * 96 + nb)) * 512;
                gload_lds16(src + lane * 8, base + 16384 + u2 * 1024);
            }
        }
    };
    auto compute = [&](int buf, bool isx) {
        uint8_t* base = smem + buf * 40960;
#pragma unroll
        for (int kbl = 0; kbl < 2; ++kbl) {
            const bf16* ab = (const bf16*)(base + (mw + 4 * kbl) * 1024) + lane * 8;
            const bf16x8 ahi = *(const bf16x8*)ab;
            const bf16x8 alo = *(const bf16x8*)(ab + 8 * 512);
            const bf16* bp = (const bf16*)(base + 16384) + lane * 8;
#pragma unroll
            for (int g = 0; g < 3; ++g) {
                const bf16x8 bhi = *(const bf16x8*)(bp + ((g * 2 + jw) + 6 * kbl) * 512);
                const bf16x8 blo = *(const bf16x8*)(bp + ((g * 2 + jw) + 6 * kbl + 12) * 512);
                f32x4* ap = (g == 0) ? &acc0 : (g == 1) ? &acc1
                          : (isx ? &acc3 : &acc2);
                *ap = MFMA_BF16(ahi, bhi, *ap);
                *ap = MFMA_BF16(alo, bhi, *ap);
                *ap = MFMA_BF16(ahi, blo, *ap);
            }
        }
    };

    stage(0, 0);
    __syncthreads();
#pragma unroll
    for (int c = 0; c < 8; ++c) {
        stage(c + 1, (c + 1) & 1);            // c==7 -> stage(8,0): x-B tiles
        if (c == 7) {
            // build x A-tiles (s 0..63, hi/lo) into buf 0 A-region for chunk 8
            uint8_t* base = smem;              // buf 0
            const int bl = tid >> 3, s0 = (tid & 7) * 8;
            const float* xs = x + ((size_t)(b0 + bl) * T_ + t) * SENSORY + s0;
            float v[8];
#pragma unroll
            for (int e = 0; e < 8; ++e) v[e] = xs[e];
            bf16x8 hv, lv;
#pragma unroll
            for (int e = 0; e < 8; ++e) {
                bf16 h = (bf16)v[e];
                hv[e] = h;
                lv[e] = (bf16)(v[e] - (float)h);
            }
            const int tile = (bl >> 4) + 4 * (s0 >> 5);
            const int sl = (((s0 >> 3) & 3) * 16 + (bl & 15)) * 16;
            *(bf16x8*)(base + tile * 1024 + sl) = hv;
            *(bf16x8*)(base + (tile + 8) * 1024 + sl) = lv;
        }
        compute(c & 1, false);
        __syncthreads();
    }
    compute(0, true);

    // ---- epilogue: gates + state update + exact s=64 rank-1 ----
    const float bihr = b_ih[jj], bihz = b_ih[H_ + jj], bihn = b_ih[2 * H_ + jj];
    const float bhhr = b_hh[jj], bhhz = b_hh[H_ + jj], bhhn = b_hh[2 * H_ + jj];
    const float w64r = w_ih[(size_t)jj * IN_DIM + 128];
    const float w64z = w_ih[(size_t)(H_ + jj) * IN_DIM + 128];
    const float w64n = w_ih[(size_t)(2 * H_ + jj) * IN_DIM + 128];
    const bool use_rule = (t < INFO_DUR);
    const size_t tb   = (size_t)(by * 64 + bx * 4 + mw) * 512;
    const int    scol = ((jj >> 3) & 3) * 16;
#pragma unroll
    for (int r = 0; r < 4; ++r) {
        const int b = bb0 + r;
        const float xv = x[((size_t)b * T_ + t) * SENSORY + 64];
        float ar = 0.f, az = 0.f, an = 0.f;
        if (use_rule) {
            const float* rg = rule_gi + (size_t)b * G3 + jj;
            ar = rg[0]; az = rg[H_]; an = rg[2 * H_];
        }
        const float rr = sigmoidf_(acc0[r] + bihr + bhhr + ar + xv * w64r);
        const float zz = sigmoidf_(acc1[r] + bihz + bhhz + az + xv * w64z);
        const float hn = acc2[r] + bhhn;
        const float in = acc3[r] + bihn + an + xv * w64n;
        const float nn = fmaxf(in + rr * hn, 0.f);
        const float ho = h_src[(size_t)b * hs_stride + jj];
        const float hnew = (1.f - zz) * nn + zz * ho;
        hid[(size_t)b * (T_ * H_) + (size_t)t * H_ + jj] = hnew;
        const bf16 hi = (bf16)hnew;
        const bf16 lo = (bf16)(hnew - (float)hi);
        const size_t ha = tb + (size_t)(scol + (b & 15)) * 8 + (jj & 7);
        hout_hi[ha] = hi;
        hout_lo[ha] = lo;
    }
}

// ---------------------------------------------------------------------------
// out = sigmoid(hid @ out_w^T + b): MFMA, N padded 33->48, 64 rows/block.
__global__ void __launch_bounds__(256) out_kernel(
    const float* __restrict__ hid,
    const bf16* __restrict__ owhi, const bf16* __restrict__ owlo,
    const float* __restrict__ out_b, float* __restrict__ out)
{
    __shared__ __align__(16) unsigned char smem[28672];
    bf16* const A  = (bf16*)smem;            // 16 tiles: mbl + 4*kbl + 8*hh
    bf16* const Bf = (bf16*)(smem + 16384);  // 12 tiles: nbl + 3*kbl + 6*hh
    const int tid = threadIdx.x, w = tid >> 6, lane = tid & 63;
    const int bt0 = blockIdx.x * 64;

    f32x4 acc0 = {0.f, 0.f, 0.f, 0.f};
    f32x4 acc1 = {0.f, 0.f, 0.f, 0.f};
    f32x4 acc2 = {0.f, 0.f, 0.f, 0.f};

#pragma unroll 1
    for (int c = 0; c < 8; ++c) {            // K chunks of 64
        __syncthreads();
#pragma unroll
        for (int i = 0; i < 3; ++i) {
            const int u = w * 3 + i;
            const int nbl = u % 3, kbl = (u / 3) & 1, hh = u / 6;
            const bf16* src = (hh ? owlo : owhi)
                + ((size_t)((2 * c + kbl) * 3 + nbl)) * 512 + lane * 8;
            gload_lds16(src, Bf + u * 512);
        }
#pragma unroll
        for (int it = 0; it < 2; ++it) {
            const int v = tid + it * 256;
            const int row = v >> 3, kq = v & 7;
            const float* src = hid + (size_t)(bt0 + row) * H_ + c * 64 + kq * 8;
            const f32x4 v0 = *(const f32x4*)src;
            const f32x4 v1 = *(const f32x4*)(src + 4);
            bf16x8 hv, lv;
#pragma unroll
            for (int e = 0; e < 4; ++e) {
                bf16 h0 = (bf16)v0[e]; hv[e] = h0;     lv[e] = (bf16)(v0[e] - (float)h0);
                bf16 h1 = (bf16)v1[e]; hv[4 + e] = h1; lv[4 + e] = (bf16)(v1[e] - (float)h1);
            }
            const int at = (row >> 4) + 4 * (kq >> 2);
            const int sl = ((kq & 3) * 16 + (row & 15)) * 8;
            *(bf16x8*)(A + at * 512 + sl) = hv;
            *(bf16x8*)(A + (at + 8) * 512 + sl) = lv;
        }
        __syncthreads();
#pragma unroll
        for (int kbl = 0; kbl < 2; ++kbl) {
            const bf16* ab = A + (w + 4 * kbl) * 512 + lane * 8;
            const bf16x8 ahi = *(const bf16x8*)ab;
            const bf16x8 alo = *(const bf16x8*)(ab + 8 * 512);
            const bf16* bb = Bf + (3 * kbl) * 512 + lane * 8;
            {   const bf16x8 bhi = *(const bf16x8*)bb;
                const bf16x8 blo = *(const bf16x8*)(bb + 6 * 512);
                acc0 = MFMA_BF16(ahi, bhi, acc0);
                acc0 = MFMA_BF16(alo, bhi, acc0);
                acc0 = MFMA_BF16(ahi, blo, acc0); }
            {   const bf16x8 bhi = *(const bf16x8*)(bb + 512);
                const bf16x8 blo = *(const bf16x8*)(bb + 7 * 512);
                acc1 = MFMA_BF16(ahi, bhi, acc1);
                acc1 = MFMA_BF16(alo, bhi, acc1);
                acc1 = MFMA_BF16(ahi, blo, acc1); }
            {   const bf16x8 bhi = *(const bf16x8*)(bb + 2 * 512);
                const bf16x8 blo = *(const bf16x8*)(bb + 8 * 512);
                acc2 = MFMA_BF16(ahi, bhi, acc2);
                acc2 = MFMA_BF16(alo, bhi, acc2);
                acc2 = MFMA_BF16(ahi, blo, acc2); }
        }
    }
    const int col = lane & 15, rb = (lane >> 4) * 4;
#pragma unroll
    for (int nb = 0; nb < 3; ++nb) {
        const int o = nb * 16 + col;
        if (o < OUT_) {
            const float ob = out_b[o];
            const f32x4 a = (nb == 0) ? acc0 : (nb == 1) ? acc1 : acc2;
#pragma unroll
            for (int r = 0; r < 4; ++r) {
                const int row = bt0 + w * 16 + rb + r;
                out[(size_t)row * OUT_ + o] = sigmoidf_(a[r] + ob);
            }
        }
    }
}

// ---------------------------------------------------------------------------
extern "C" void kernel_launch(void* const* d_in, const int* in_sizes, int n_in,
                              void* d_out, int out_size, void* d_ws, size_t ws_size,
                              hipStream_t stream)
{
    const float* x              = (const float*)d_in[0];
    const float* task_rule      = (const float*)d_in[1];
    const float* rule_transform = (const float*)d_in[2];
    const float* enc_w1         = (const float*)d_in[3];
    const float* enc_b1         = (const float*)d_in[4];
    const float* enc_w2         = (const float*)d_in[5];
    const float* enc_b2         = (const float*)d_in[6];
    const float* w_ih           = (const float*)d_in[7];
    const float* w_hh           = (const float*)d_in[8];
    const float* b_ih           = (const float*)d_in[9];
    const float* b_hh           = (const float*)d_in[10];
    const float* out_w          = (const float*)d_in[11];
    const float* out_b          = (const float*)d_in[12];

    float* out_p  = (float*)d_out;
    float* hid_p  = (float*)d_out + HID_OFF;
    float* renc_p = (float*)d_out + RENC_OFF;

    // workspace layout (bytes), total 16,613,376
    uint8_t* wsb = (uint8_t*)d_ws;
    float* rule_gi = (float*)(wsb + 0);            // B*G3*4   = 6,291,456
    float* hinit   = (float*)(wsb + 6291456);      // B*H*4    = 2,097,152
    bf16* hh0   = (bf16*)(wsb +  8388608);         // B*H*2    = 1,048,576 each
    bf16* hl0   = (bf16*)(wsb +  9437184);
    bf16* hh1   = (bf16*)(wsb + 10485760);
    bf16* hl1   = (bf16*)(wsb + 11534336);
    bf16* whhhi = (bf16*)(wsb + 12582912);         // G3*H*2   = 1,572,864
    bf16* whhlo = (bf16*)(wsb + 14155776);
    bf16* wihhi = (bf16*)(wsb + 15728640);         // G3*128*2 =   393,216
    bf16* wihlo = (bf16*)(wsb + 16121856);
    bf16* owhi  = (bf16*)(wsb + 16515072);         // 48*512*2 =    49,152
    bf16* owlo  = (bf16*)(wsb + 16564224);

    init_h_kernel<<<(B_ * H_) / 256, 256, 0, stream>>>(hinit, hh0, hl0);
    whh_prep_kernel<<<384, 256, 0, stream>>>(w_hh, whhhi, whhlo);
    wih_prep_kernel<<<96, 256, 0, stream>>>(w_ih, wihhi, wihlo);
    outw_prep_kernel<<<12, 256, 0, stream>>>(out_w, owhi, owlo);
    enc_kernel<<<B_, 128, 0, stream>>>(task_rule, rule_transform, enc_w1, enc_b1,
                                       enc_w2, enc_b2, renc_p);
    rulegi_kernel<<<(B_ * G3) / 256, 256, 0, stream>>>(renc_p, w_ih, rule_gi);

    bf16* ph[2] = { hh0, hh1 };
    bf16* pl[2] = { hl0, hl1 };
    for (int t = 0; t < T_; ++t) {
        const float* hs = (t == 0) ? hinit : (hid_p + (size_t)(t - 1) * H_);
        int stride      = (t == 0) ? H_ : (T_ * H_);
        const int pi = t & 1, po = (t + 1) & 1;
        step_kernel<<<256, 512, 0, stream>>>(
            hid_p, hs, stride, ph[pi], pl[pi], ph[po], pl[po],
            whhhi, whhlo, wihhi, wihlo, x, rule_gi, b_ih, b_hh, w_ih, t);
    }

    out_kernel<<<(B_ * T_) / 64, 256, 0, stream>>>(hid_p, owhi, owlo, out_b, out_p);
}